// Round 1
// baseline (10438.649 us; speedup 1.0000x reference)
//
#include <hip/hip_runtime.h>
#include <stdint.h>

typedef unsigned short u16;
typedef __attribute__((ext_vector_type(8))) __bf16 bf16x8;
typedef __attribute__((ext_vector_type(4))) float f32x4;

#define NBLK 64          // recurrence blocks (each owns 16 h-columns)
#define TSTEPS 1000

__device__ __forceinline__ u16 f2bf(float f) {
    uint32_t u = __builtin_bit_cast(uint32_t, f);
    u += 0x7fffu + ((u >> 16) & 1u);
    return (u16)(u >> 16);
}
__device__ __forceinline__ float bf2f(u16 s) {
    uint32_t u = ((uint32_t)s) << 16;
    return __builtin_bit_cast(float, u);
}

// quaternion block tables: W[ci*256+a][cj*256+b] = sgn[ci][cj] * w[comp[ci][cj]][a][b]
__device__ const int   q_comp[4][4] = {{0,1,2,3},{1,0,3,2},{2,3,0,1},{3,2,1,0}};
__device__ const float q_sgn [4][4] = {{ 1.f, 1.f, 1.f, 1.f},
                                       {-1.f, 1.f, 1.f,-1.f},
                                       {-1.f,-1.f, 1.f, 1.f},
                                       {-1.f, 1.f,-1.f, 1.f}};

// ---------------- x (f32) -> bf16 ----------------
__global__ void k_convert_x(const float* __restrict__ x, u16* __restrict__ xb, int n8) {
    int i = blockIdx.x * blockDim.x + threadIdx.x;
    if (i >= n8) return;
    const float4* p = (const float4*)x;
    float4 v0 = p[2*i], v1 = p[2*i + 1];
    u16 o[8];
    o[0]=f2bf(v0.x); o[1]=f2bf(v0.y); o[2]=f2bf(v0.z); o[3]=f2bf(v0.w);
    o[4]=f2bf(v1.x); o[5]=f2bf(v1.y); o[6]=f2bf(v1.z); o[7]=f2bf(v1.w);
    *(uint4*)(xb + (size_t)i*8) = *(uint4*)o;
}

// ---------------- build WqT [2048][1024] bf16 (row n = output col, k-contiguous) -----
__global__ void k_build_wq(const float* __restrict__ wh_w, const float* __restrict__ wz_w,
                           u16* __restrict__ wqT) {
    int tid = blockIdx.x * blockDim.x + threadIdx.x;   // 0..262143
    int n = tid >> 7, kg = tid & 127;
    const float* src = (n < 1024) ? wh_w : wz_w;
    int nn = n & 1023;
    int cj = nn >> 8, b = nn & 255;
    int k0 = kg << 3;
    int ci = k0 >> 8, a0 = k0 & 255;
    int c = q_comp[ci][cj];
    float s = q_sgn[ci][cj];
    const float* sp = src + c*65536 + a0*256 + b;
    u16 o[8];
    #pragma unroll
    for (int e = 0; e < 8; ++e) o[e] = f2bf(s * sp[e*256]);
    *(uint4*)(wqT + (size_t)n*1024 + k0) = *(uint4*)o;
}

// ---------------- build U pack: [blk][nt][ks][lane][8] bf16 (MFMA B-fragment order) --
__global__ void k_build_upack(const float* __restrict__ uh_w, const float* __restrict__ uz_w,
                              u16* __restrict__ upack) {
    int tid = blockIdx.x * blockDim.x + threadIdx.x;   // 0..262143
    int l   = tid & 63;
    int ks  = (tid >> 6) & 31;
    int nt  = (tid >> 11) & 1;
    int blk = tid >> 12;
    int j   = (blk << 4) + (l & 15);        // U column
    int k0  = (ks << 5) + ((l >> 4) << 3);  // U row base
    int ci = k0 >> 8, a0 = k0 & 255;
    int cj = j >> 8, b = j & 255;
    const float* src = nt ? uz_w : uh_w;
    int c = q_comp[ci][cj];
    float s = q_sgn[ci][cj];
    const float* sp = src + c*65536 + a0*256 + b;
    u16 o[8];
    #pragma unroll
    for (int e = 0; e < 8; ++e) o[e] = f2bf(s * sp[e*256]);
    *(uint4*)(upack + (size_t)tid*8) = *(uint4*)o;
}

// ---------------- phase-1 GEMM: C[32000][2048] bf16 = x_bf16 @ WqT^T + bias ----------
__global__ __launch_bounds__(256) void k_gemm(
        const u16* __restrict__ A, const u16* __restrict__ Bt,
        const float* __restrict__ whb, const float* __restrict__ wzb,
        u16* __restrict__ C)
{
    __shared__ __align__(16) u16 lsA[128*32];
    __shared__ __align__(16) u16 lsB[128*32];
    int bid = blockIdx.x;
    int swz = (bid & 7) * 500 + (bid >> 3);   // XCD swizzle (4000 = 8*500, bijective)
    int mi = swz >> 4, ni = swz & 15;
    int m0 = mi << 7, n0 = ni << 7;
    int tid = threadIdx.x;
    int w = tid >> 6, l = tid & 63;
    int wm = w >> 1, wn = w & 1;
    f32x4 acc[4][4];
    #pragma unroll
    for (int i = 0; i < 4; ++i)
        #pragma unroll
        for (int j = 0; j < 4; ++j) acc[i][j] = (f32x4){0.f,0.f,0.f,0.f};

    for (int kt = 0; kt < 32; ++kt) {
        int k0 = kt << 5;
        #pragma unroll
        for (int r = 0; r < 2; ++r) {
            int c = r*256 + w*64 + l;
            const u16* ga = A + (size_t)(m0 + (c >> 2))*1024 + k0 + (c & 3)*8;
            __builtin_amdgcn_global_load_lds(
                (const __attribute__((address_space(1))) uint32_t*)ga,
                (__attribute__((address_space(3))) uint32_t*)((char*)lsA + r*4096 + w*1024),
                16, 0, 0);
            const u16* gb = Bt + (size_t)(n0 + (c >> 2))*1024 + k0 + (c & 3)*8;
            __builtin_amdgcn_global_load_lds(
                (const __attribute__((address_space(1))) uint32_t*)gb,
                (__attribute__((address_space(3))) uint32_t*)((char*)lsB + r*4096 + w*1024),
                16, 0, 0);
        }
        __syncthreads();
        uint4 af[4], bfr[4];
        #pragma unroll
        for (int i = 0; i < 4; ++i) {
            int rowa = wm*64 + i*16 + (l & 15);
            af[i]  = *(const uint4*)((const char*)lsA + rowa*64 + (l >> 4)*16);
            int rowb = wn*64 + i*16 + (l & 15);
            bfr[i] = *(const uint4*)((const char*)lsB + rowb*64 + (l >> 4)*16);
        }
        #pragma unroll
        for (int i = 0; i < 4; ++i)
            #pragma unroll
            for (int j = 0; j < 4; ++j)
                acc[i][j] = __builtin_amdgcn_mfma_f32_16x16x32_bf16(
                    __builtin_bit_cast(bf16x8, af[i]),
                    __builtin_bit_cast(bf16x8, bfr[j]),
                    acc[i][j], 0, 0, 0);
        __syncthreads();
    }
    #pragma unroll
    for (int j = 0; j < 4; ++j) {
        int col = n0 + wn*64 + j*16 + (l & 15);
        float bias = (col < 1024) ? whb[col] : wzb[col - 1024];
        #pragma unroll
        for (int i = 0; i < 4; ++i) {
            int rowm = m0 + wm*64 + i*16 + ((l >> 4) << 2);
            #pragma unroll
            for (int q = 0; q < 4; ++q)
                C[(size_t)(rowm + q)*2048 + col] = f2bf(acc[i][j][q] + bias);
        }
    }
}

// ---------------- phase-2: the recurrence -------------------------------------------
// 64 blocks x 128 threads. Block owns 16 h-columns; U slice lives in LDS.
// h_t exchanged via hbuf (A-fragment-packed bf16, double buffered) + counter barrier.
__global__ __launch_bounds__(128) void k_rec(
        const u16* __restrict__ upack,
        u16* __restrict__ hbuf,            // 2 * 32768 u16
        uint32_t* __restrict__ ctr,        // >= 1001 u32, zeroed
        const float* __restrict__ drop,    // [32][1024]
        float* __restrict__ out)           // d_out; also holds phase-1 bf16 [32000][2048]
{
    __shared__ __align__(16) uint4 ubs[4096];     // 64 KB U slice
    const int tid = threadIdx.x;
    const int blk = blockIdx.x;
    const int mt = tid >> 6, l = tid & 63;

    const uint4* ug = (const uint4*)upack + (size_t)blk*4096;
    #pragma unroll 4
    for (int r = 0; r < 32; ++r) ubs[r*128 + tid] = ug[r*128 + tid];

    const int j  = (blk << 4) + (l & 15);
    const int b0 = (mt << 4) + ((l >> 4) << 2);
    float h[4] = {0.f,0.f,0.f,0.f};
    float dm[4];
    #pragma unroll
    for (int q = 0; q < 4; ++q) dm[q] = drop[(b0 + q)*1024 + j];

    const u16* pj = (const u16*)out;   // [32000][2048] bf16 (phase-1 result)
    u16 whu[4], wzu[4];
    #pragma unroll
    for (int q = 0; q < 4; ++q) {      // prefetch projections for t=0
        size_t row = (size_t)(b0 + q) * 2048;
        whu[q] = pj[row + j];
        wzu[q] = pj[row + 1024 + j];
    }
    // producer offset into packed hbuf for (b0+q, j)
    const int hoff = ((mt*32 + (j >> 5))*64 + (((j >> 3) & 3)*16 + ((l >> 4) << 2)))*8 + (j & 7);

    __syncthreads();
    __threadfence();
    if (tid == 0)
        __hip_atomic_fetch_add(&ctr[0], 1u, __ATOMIC_RELEASE, __HIP_MEMORY_SCOPE_AGENT);

    for (int t = 0; t < TSTEPS; ++t) {
        if (tid == 0) {
            while (__hip_atomic_load(&ctr[t], __ATOMIC_ACQUIRE, __HIP_MEMORY_SCOPE_AGENT) < NBLK)
                __builtin_amdgcn_s_sleep(1);
        }
        __syncthreads();
        __threadfence();   // acquire: invalidate stale L1/L2 before reading peers' h

        const u16* hb  = hbuf + ((t & 1) << 15);
        u16*       hbn = hbuf + (((t + 1) & 1) << 15);
        uint4 areg[32];
        #pragma unroll
        for (int ks = 0; ks < 32; ++ks)
            areg[ks] = *(const uint4*)(hb + (((mt*32 + ks)*64 + l) << 3));

        u16 nwh[4], nwz[4];
        if (t < TSTEPS - 1) {          // prefetch next step's projections (region t+1,
            #pragma unroll             // safe: completes before we arrive at ctr[t+1])
            for (int q = 0; q < 4; ++q) {
                size_t row = (size_t)((t + 1)*32 + b0 + q) * 2048;
                nwh[q] = pj[row + j];
                nwz[q] = pj[row + 1024 + j];
            }
        }

        f32x4 acch = {0.f,0.f,0.f,0.f}, accz = {0.f,0.f,0.f,0.f};
        #pragma unroll
        for (int ks = 0; ks < 32; ++ks) {
            bf16x8 av = __builtin_bit_cast(bf16x8, areg[ks]);
            bf16x8 bh = __builtin_bit_cast(bf16x8, ubs[ks*64 + l]);
            bf16x8 bz = __builtin_bit_cast(bf16x8, ubs[(32 + ks)*64 + l]);
            acch = __builtin_amdgcn_mfma_f32_16x16x32_bf16(av, bh, acch, 0, 0, 0);
            accz = __builtin_amdgcn_mfma_f32_16x16x32_bf16(av, bz, accz, 0, 0, 0);
        }

        const size_t orow = (size_t)t << 15;    // t*32*1024
        #pragma unroll
        for (int q = 0; q < 4; ++q) {
            float a  = acch[q] + bf2f(whu[q]);
            float zl = accz[q] + bf2f(wzu[q]);
            float z  = 1.0f / (1.0f + __expf(-zl));
            float hc = fmaxf(a, 0.0f) * dm[q];
            float hn = z * h[q] + (1.0f - z) * hc;
            h[q] = hn;
            out[orow + (size_t)(b0 + q)*1024 + j] = hn;   // f32 result
            hbn[hoff + (q << 3)] = f2bf(hn);              // bf16 for next matmul
        }
        if (t < TSTEPS - 1) {
            #pragma unroll
            for (int q = 0; q < 4; ++q) { whu[q] = nwh[q]; wzu[q] = nwz[q]; }
        }

        __threadfence();   // release: h-slice + loads drained before arrival
        __syncthreads();
        if (tid == 0)
            __hip_atomic_fetch_add(&ctr[t + 1], 1u, __ATOMIC_RELEASE, __HIP_MEMORY_SCOPE_AGENT);
    }
}

extern "C" void kernel_launch(void* const* d_in, const int* in_sizes, int n_in,
                              void* d_out, int out_size, void* d_ws, size_t ws_size,
                              hipStream_t stream) {
    const float* x    = (const float*)d_in[0];
    const float* wh_w = (const float*)d_in[1];
    const float* wh_b = (const float*)d_in[2];
    const float* wz_w = (const float*)d_in[3];
    const float* wz_b = (const float*)d_in[4];
    const float* uh_w = (const float*)d_in[5];
    const float* uz_w = (const float*)d_in[6];
    const float* drop = (const float*)d_in[7];

    char* ws = (char*)d_ws;
    u16*      xb    = (u16*)ws;                               // 65,536,000 B
    u16*      wqT   = (u16*)(ws + 65536000);                  //  4,194,304 B
    u16*      upack = (u16*)(ws + 65536000 + 4194304);        //  4,194,304 B
    u16*      hbuf  = (u16*)(ws + 65536000 + 8388608);        //    131,072 B
    uint32_t* ctr   = (uint32_t*)(ws + 65536000 + 8388608 + 131072); // 4,096 B

    hipMemsetAsync(ctr, 0, 4096, stream);
    hipMemsetAsync(hbuf, 0, 65536, stream);     // h_0 = 0 (buffer parity 0)

    k_convert_x  <<<16000, 256, 0, stream>>>(x, xb, 4096000);
    k_build_wq   <<<1024, 256, 0, stream>>>(wh_w, wz_w, wqT);
    k_build_upack<<<1024, 256, 0, stream>>>(uh_w, uz_w, upack);
    k_gemm       <<<4000, 256, 0, stream>>>(xb, wqT, wh_b, wz_b, (u16*)d_out);
    k_rec        <<<NBLK, 128, 0, stream>>>(upack, hbuf, ctr, drop, (float*)d_out);
}

// Round 2
// 4851.974 us; speedup vs baseline: 2.1514x; 2.1514x over previous
//
#include <hip/hip_runtime.h>
#include <stdint.h>

typedef unsigned short u16;
typedef __attribute__((ext_vector_type(8))) __bf16 bf16x8;
typedef __attribute__((ext_vector_type(4))) float f32x4;

#define NBLK 64          // recurrence blocks (each owns 16 h-columns)
#define TSTEPS 1000

__device__ __forceinline__ u16 f2bf(float f) {
    uint32_t u = __builtin_bit_cast(uint32_t, f);
    u += 0x7fffu + ((u >> 16) & 1u);
    return (u16)(u >> 16);
}
__device__ __forceinline__ float bf2f(u16 s) {
    uint32_t u = ((uint32_t)s) << 16;
    return __builtin_bit_cast(float, u);
}

// write-through to coherence point (bypass L2 ownership): visible device-wide
__device__ __forceinline__ void store_u16_sc(u16* p, u16 v) {
    asm volatile("global_store_short %0, %1, off sc0 sc1"
                 :: "v"(p), "v"((uint32_t)v) : "memory");
}

// quaternion block tables: W[ci*256+a][cj*256+b] = sgn[ci][cj] * w[comp[ci][cj]][a][b]
__device__ const int   q_comp[4][4] = {{0,1,2,3},{1,0,3,2},{2,3,0,1},{3,2,1,0}};
__device__ const float q_sgn [4][4] = {{ 1.f, 1.f, 1.f, 1.f},
                                       {-1.f, 1.f, 1.f,-1.f},
                                       {-1.f,-1.f, 1.f, 1.f},
                                       {-1.f, 1.f,-1.f, 1.f}};

// ---------------- x (f32) -> bf16 ----------------
__global__ void k_convert_x(const float* __restrict__ x, u16* __restrict__ xb, int n8) {
    int i = blockIdx.x * blockDim.x + threadIdx.x;
    if (i >= n8) return;
    const float4* p = (const float4*)x;
    float4 v0 = p[2*i], v1 = p[2*i + 1];
    u16 o[8];
    o[0]=f2bf(v0.x); o[1]=f2bf(v0.y); o[2]=f2bf(v0.z); o[3]=f2bf(v0.w);
    o[4]=f2bf(v1.x); o[5]=f2bf(v1.y); o[6]=f2bf(v1.z); o[7]=f2bf(v1.w);
    *(uint4*)(xb + (size_t)i*8) = *(uint4*)o;
}

// ---------------- build WqT [2048][1024] bf16 (row n = output col, k-contiguous) -----
__global__ void k_build_wq(const float* __restrict__ wh_w, const float* __restrict__ wz_w,
                           u16* __restrict__ wqT) {
    int tid = blockIdx.x * blockDim.x + threadIdx.x;   // 0..262143
    int n = tid >> 7, kg = tid & 127;
    const float* src = (n < 1024) ? wh_w : wz_w;
    int nn = n & 1023;
    int cj = nn >> 8, b = nn & 255;
    int k0 = kg << 3;
    int ci = k0 >> 8, a0 = k0 & 255;
    int c = q_comp[ci][cj];
    float s = q_sgn[ci][cj];
    const float* sp = src + c*65536 + a0*256 + b;
    u16 o[8];
    #pragma unroll
    for (int e = 0; e < 8; ++e) o[e] = f2bf(s * sp[e*256]);
    *(uint4*)(wqT + (size_t)n*1024 + k0) = *(uint4*)o;
}

// ---------------- build U pack: [blk][nt][ks][lane][8] bf16 (MFMA B-fragment order) --
__global__ void k_build_upack(const float* __restrict__ uh_w, const float* __restrict__ uz_w,
                              u16* __restrict__ upack) {
    int tid = blockIdx.x * blockDim.x + threadIdx.x;   // 0..262143
    int l   = tid & 63;
    int ks  = (tid >> 6) & 31;
    int nt  = (tid >> 11) & 1;
    int blk = tid >> 12;
    int j   = (blk << 4) + (l & 15);        // U column
    int k0  = (ks << 5) + ((l >> 4) << 3);  // U row base
    int ci = k0 >> 8, a0 = k0 & 255;
    int cj = j >> 8, b = j & 255;
    const float* src = nt ? uz_w : uh_w;
    int c = q_comp[ci][cj];
    float s = q_sgn[ci][cj];
    const float* sp = src + c*65536 + a0*256 + b;
    u16 o[8];
    #pragma unroll
    for (int e = 0; e < 8; ++e) o[e] = f2bf(s * sp[e*256]);
    *(uint4*)(upack + (size_t)tid*8) = *(uint4*)o;
}

// ---------------- phase-1 GEMM: C[32000][2048] bf16 = x_bf16 @ WqT^T + bias ----------
__global__ __launch_bounds__(256) void k_gemm(
        const u16* __restrict__ A, const u16* __restrict__ Bt,
        const float* __restrict__ whb, const float* __restrict__ wzb,
        u16* __restrict__ C)
{
    __shared__ __align__(16) u16 lsA[128*32];
    __shared__ __align__(16) u16 lsB[128*32];
    int bid = blockIdx.x;
    int swz = (bid & 7) * 500 + (bid >> 3);   // XCD swizzle (4000 = 8*500, bijective)
    int mi = swz >> 4, ni = swz & 15;
    int m0 = mi << 7, n0 = ni << 7;
    int tid = threadIdx.x;
    int w = tid >> 6, l = tid & 63;
    int wm = w >> 1, wn = w & 1;
    f32x4 acc[4][4];
    #pragma unroll
    for (int i = 0; i < 4; ++i)
        #pragma unroll
        for (int j = 0; j < 4; ++j) acc[i][j] = (f32x4){0.f,0.f,0.f,0.f};

    for (int kt = 0; kt < 32; ++kt) {
        int k0 = kt << 5;
        #pragma unroll
        for (int r = 0; r < 2; ++r) {
            int c = r*256 + w*64 + l;
            const u16* ga = A + (size_t)(m0 + (c >> 2))*1024 + k0 + (c & 3)*8;
            __builtin_amdgcn_global_load_lds(
                (const __attribute__((address_space(1))) uint32_t*)ga,
                (__attribute__((address_space(3))) uint32_t*)((char*)lsA + r*4096 + w*1024),
                16, 0, 0);
            const u16* gb = Bt + (size_t)(n0 + (c >> 2))*1024 + k0 + (c & 3)*8;
            __builtin_amdgcn_global_load_lds(
                (const __attribute__((address_space(1))) uint32_t*)gb,
                (__attribute__((address_space(3))) uint32_t*)((char*)lsB + r*4096 + w*1024),
                16, 0, 0);
        }
        __syncthreads();
        uint4 af[4], bfr[4];
        #pragma unroll
        for (int i = 0; i < 4; ++i) {
            int rowa = wm*64 + i*16 + (l & 15);
            af[i]  = *(const uint4*)((const char*)lsA + rowa*64 + (l >> 4)*16);
            int rowb = wn*64 + i*16 + (l & 15);
            bfr[i] = *(const uint4*)((const char*)lsB + rowb*64 + (l >> 4)*16);
        }
        #pragma unroll
        for (int i = 0; i < 4; ++i)
            #pragma unroll
            for (int j = 0; j < 4; ++j)
                acc[i][j] = __builtin_amdgcn_mfma_f32_16x16x32_bf16(
                    __builtin_bit_cast(bf16x8, af[i]),
                    __builtin_bit_cast(bf16x8, bfr[j]),
                    acc[i][j], 0, 0, 0);
        __syncthreads();
    }
    #pragma unroll
    for (int j = 0; j < 4; ++j) {
        int col = n0 + wn*64 + j*16 + (l & 15);
        float bias = (col < 1024) ? whb[col] : wzb[col - 1024];
        #pragma unroll
        for (int i = 0; i < 4; ++i) {
            int rowm = m0 + wm*64 + i*16 + ((l >> 4) << 2);
            #pragma unroll
            for (int q = 0; q < 4; ++q)
                C[(size_t)(rowm + q)*2048 + col] = f2bf(acc[i][j][q] + bias);
        }
    }
}

// ---------------- phase-2: the recurrence -------------------------------------------
// 64 blocks x 128 threads (2 waves). Block owns 16 h-columns; U slice in LDS.
// Per-wave distributed flag barrier + sc1 (coherence-point) data exchange.
// No threadfence / no atomic RMW / no __syncthreads in the loop.
__global__ __launch_bounds__(128) void k_rec(
        const u16* __restrict__ upack,
        u16* __restrict__ hbuf,            // 2 * 32768 u16, parity 0 zeroed
        uint32_t* __restrict__ flags,      // 128 u32, zeroed
        const float* __restrict__ drop,    // [32][1024]
        float* __restrict__ out)           // d_out; also holds phase-1 bf16 [32000][2048]
{
    __shared__ __align__(16) uint4 ubs[4096];     // 64 KB U slice
    const int tid = threadIdx.x;
    const int blk = blockIdx.x;
    const int mt = tid >> 6, l = tid & 63;
    const int wid = (blk << 1) + mt;              // wave id 0..127

    const uint4* ug = (const uint4*)upack + (size_t)blk*4096;
    #pragma unroll 4
    for (int r = 0; r < 32; ++r) ubs[r*128 + tid] = ug[r*128 + tid];

    const int j  = (blk << 4) + (l & 15);
    const int b0 = (mt << 4) + ((l >> 4) << 2);
    float h[4] = {0.f,0.f,0.f,0.f};
    float dm[4];
    #pragma unroll
    for (int q = 0; q < 4; ++q) dm[q] = drop[(b0 + q)*1024 + j];

    const u16* pj = (const u16*)out;   // [32000][2048] bf16 (phase-1 result)
    u16 whu[4], wzu[4];
    #pragma unroll
    for (int q = 0; q < 4; ++q) {      // projections for t=0
        size_t row = (size_t)(b0 + q) * 2048;
        whu[q] = pj[row + j];
        wzu[q] = pj[row + 1024 + j];
    }
    // producer offset into packed hbuf for (b0+q, j)
    const int hoff = ((mt*32 + (j >> 5))*64 + (((j >> 3) & 3)*16 + ((l >> 4) << 2)))*8 + (j & 7);

    __syncthreads();   // ubs ready (only sync outside the loop)

    for (int t = 0; t < TSTEPS; ++t) {
        // prefetch next step's projections (independent of the barrier)
        u16 nwh[4], nwz[4];
        if (t < TSTEPS - 1) {
            #pragma unroll
            for (int q = 0; q < 4; ++q) {
                size_t row = (size_t)((t + 1)*32 + b0 + q) * 2048;
                nwh[q] = pj[row + j];
                nwz[q] = pj[row + 1024 + j];
            }
        }

        // distributed barrier: wait until every wave has published h_t
        if (t > 0) {
            bool ok;
            do {
                unsigned long long v = __hip_atomic_load(
                    (const unsigned long long*)(flags + 2*l),
                    __ATOMIC_RELAXED, __HIP_MEMORY_SCOPE_AGENT);
                ok = ((uint32_t)v >= (uint32_t)t) && ((uint32_t)(v >> 32) >= (uint32_t)t);
            } while (!__all(ok));
            asm volatile("" ::: "memory");
            __builtin_amdgcn_sched_barrier(0);
        }

        const u16* hb  = hbuf + ((t & 1) << 15);
        u16*       hbn = hbuf + (((t + 1) & 1) << 15);

        f32x4 acch = {0.f,0.f,0.f,0.f}, accz = {0.f,0.f,0.f,0.f};
        #pragma unroll
        for (int ks = 0; ks < 32; ++ks) {
            const u16* p = hb + (((mt*32 + ks)*64 + l) << 3);
            unsigned long long lo = __hip_atomic_load((const unsigned long long*)p,
                __ATOMIC_RELAXED, __HIP_MEMORY_SCOPE_AGENT);
            unsigned long long hi = __hip_atomic_load((const unsigned long long*)(p + 4),
                __ATOMIC_RELAXED, __HIP_MEMORY_SCOPE_AGENT);
            uint4 av4 = {(uint32_t)lo, (uint32_t)(lo >> 32),
                         (uint32_t)hi, (uint32_t)(hi >> 32)};
            bf16x8 av = __builtin_bit_cast(bf16x8, av4);
            bf16x8 bh = __builtin_bit_cast(bf16x8, ubs[ks*64 + l]);
            bf16x8 bz = __builtin_bit_cast(bf16x8, ubs[(32 + ks)*64 + l]);
            acch = __builtin_amdgcn_mfma_f32_16x16x32_bf16(av, bh, acch, 0, 0, 0);
            accz = __builtin_amdgcn_mfma_f32_16x16x32_bf16(av, bz, accz, 0, 0, 0);
        }

        const size_t orow = (size_t)t << 15;    // t*32*1024
        #pragma unroll
        for (int q = 0; q < 4; ++q) {
            float a  = acch[q] + bf2f(whu[q]);
            float zl = accz[q] + bf2f(wzu[q]);
            float z  = 1.0f / (1.0f + __expf(-zl));
            float hc = fmaxf(a, 0.0f) * dm[q];
            float hn = z * h[q] + (1.0f - z) * hc;
            h[q] = hn;
            out[orow + (size_t)(b0 + q)*1024 + j] = hn;       // f32 result (plain store)
            store_u16_sc(hbn + hoff + (q << 3), f2bf(hn));    // coherent bf16 for peers
        }
        if (t < TSTEPS - 1) {
            #pragma unroll
            for (int q = 0; q < 4; ++q) { whu[q] = nwh[q]; wzu[q] = nwz[q]; }
        }

        // publish: drain all vmem (loads+stores), then set this wave's flag
        asm volatile("s_waitcnt vmcnt(0)" ::: "memory");
        if (l == 0)
            __hip_atomic_store(&flags[wid], (uint32_t)(t + 1),
                               __ATOMIC_RELAXED, __HIP_MEMORY_SCOPE_AGENT);
    }
}

extern "C" void kernel_launch(void* const* d_in, const int* in_sizes, int n_in,
                              void* d_out, int out_size, void* d_ws, size_t ws_size,
                              hipStream_t stream) {
    const float* x    = (const float*)d_in[0];
    const float* wh_w = (const float*)d_in[1];
    const float* wh_b = (const float*)d_in[2];
    const float* wz_w = (const float*)d_in[3];
    const float* wz_b = (const float*)d_in[4];
    const float* uh_w = (const float*)d_in[5];
    const float* uz_w = (const float*)d_in[6];
    const float* drop = (const float*)d_in[7];

    char* ws = (char*)d_ws;
    u16*      xb    = (u16*)ws;                               // 65,536,000 B
    u16*      wqT   = (u16*)(ws + 65536000);                  //  4,194,304 B
    u16*      upack = (u16*)(ws + 65536000 + 4194304);        //  4,194,304 B
    u16*      hbuf  = (u16*)(ws + 65536000 + 8388608);        //    131,072 B
    uint32_t* flg   = (uint32_t*)(ws + 65536000 + 8388608 + 131072); // 4,096 B

    hipMemsetAsync(flg, 0, 4096, stream);
    hipMemsetAsync(hbuf, 0, 65536, stream);     // h_0 = 0 (buffer parity 0)

    k_convert_x  <<<16000, 256, 0, stream>>>(x, xb, 4096000);
    k_build_wq   <<<1024, 256, 0, stream>>>(wh_w, wz_w, wqT);
    k_build_upack<<<1024, 256, 0, stream>>>(uh_w, uz_w, upack);
    k_gemm       <<<4000, 256, 0, stream>>>(xb, wqT, wh_b, wz_b, (u16*)d_out);
    k_rec        <<<NBLK, 128, 0, stream>>>(upack, hbuf, flg, drop, (float*)d_out);
}